// Round 13
// baseline (319.865 us; speedup 1.0000x reference)
//
#include <hip/hip_runtime.h>
#include <math.h>

// Clifford spectral conv: B=4, D=H=W=48, Cin=Cout=24, 16 modes/axis.
// q = ci*4 + c indexes 96 complex channels; d_c = x[...,c] + i*x[...,7-c].
// Radix-3 (48=3*16) DFT/iDFT, compile-time twiddle recurrence in registers.
// ALL intermediates packed fp16 complex (uint32). einsum ci-split x2.
// R13 = R12 + __builtin_nontemporal_load on ALL single-use read streams
// (x, A, Bv, wgt, OMz, IS1, IS2). Cv is re-read ~24x by einsum -> cached.
// NT *stores* are intentionally absent (R5 lesson: partial-sector NT store
// on out cost ~+25us via DRAM RMW).
// Layouts (R8): A [bd][k3][h][q], Bv [b][k2k3][d][q], IS1 [b][d][k3][k2][q].

#define C866 0.8660254037844386f

constexpr float FC0[8] = {1.0f, 0.99144486137885f, 0.96592582628907f, 0.92387953251129f,
                          0.86602540378444f, 0.79335334029124f, 0.70710678118655f, 0.60876142900872f};
constexpr float FS0[8] = {0.0f, 0.13052619222005f, 0.25881904510252f, 0.38268343236509f,
                          0.5f, 0.60876142900872f, 0.70710678118655f, 0.79335334029124f};
constexpr float FC1[8] = {0.5f, 0.60876142900872f, 0.70710678118655f, 0.79335334029124f,
                          0.86602540378444f, 0.92387953251129f, 0.96592582628907f, 0.99144486137885f};
constexpr float FS1[8] = {-0.86602540378444f, -0.79335334029124f, -0.70710678118655f, -0.60876142900872f,
                          -0.5f, -0.38268343236509f, -0.25881904510252f, -0.13052619222005f};

__device__ __forceinline__ uint32_t c2h(float2 z) {
  union { _Float16 h[2]; uint32_t u; } v;
  v.h[0] = (_Float16)z.x; v.h[1] = (_Float16)z.y;
  return v.u;
}
__device__ __forceinline__ float2 h2c(uint32_t u) {
  union { uint32_t u; _Float16 h[2]; } v;
  v.u = u;
  return make_float2((float)v.h[0], (float)v.h[1]);
}

__device__ __forceinline__ float2 cmul(float2 a, float2 b) {
  return make_float2(fmaf(a.x, b.x, -(a.y * b.y)), fmaf(a.x, b.y, a.y * b.x));
}
__device__ __forceinline__ void cfma(float2& acc, float2 a, float2 t) {
  acc.x = fmaf(a.x, t.x, acc.x); acc.x = fmaf(-a.y, t.y, acc.x);
  acc.y = fmaf(a.x, t.y, acc.y); acc.y = fmaf(a.y, t.x, acc.y);
}

// ---------------- forward DFT core: 48 inputs -> 8 modes (this thread's half)
struct FwdState {
  float2 acc[8], t[8], stp[8];
  float2 R1, R2;
};

__device__ __forceinline__ void fwd_init(FwdState& st, int half) {
#pragma unroll
  for (int r = 0; r < 8; ++r) {
    st.acc[r] = make_float2(0.f, 0.f);
    st.t[r] = make_float2(1.f, 0.f);
    st.stp[r] = make_float2(half ? FC1[r] : FC0[r],
                            half ? -FS1[r] : -FS0[r]);  // e^{-i th k}
  }
  st.R1 = half ? make_float2(-0.5f, -C866) : make_float2(1.f, 0.f);
  st.R2 = half ? make_float2(-0.5f,  C866) : make_float2(1.f, 0.f);
}

__device__ __forceinline__ void fwd_stepf(FwdState& st, float2 z0, float2 z1, float2 z2) {
  z1 = cmul(z1, st.R1);
  z2 = cmul(z2, st.R2);
  const float sx = z1.x + z2.x, sy = z1.y + z2.y;
  const float dx = z1.x - z2.x, dy = z1.y - z2.y;
  const float2 y0 = make_float2(z0.x + sx, z0.y + sy);
  const float tx = fmaf(-0.5f, sx, z0.x), ty = fmaf(-0.5f, sy, z0.y);
  const float ex = C866 * dx, ey = C866 * dy;
  const float2 y1 = make_float2(tx + ey, ty - ex);
  const float2 y2 = make_float2(tx - ey, ty + ex);
#pragma unroll
  for (int r = 0; r < 8; ++r) {
    const float2 yy = (r % 3 == 0) ? y0 : ((r % 3 == 1) ? y1 : y2);
    cfma(st.acc[r], yy, st.t[r]);
    st.t[r] = cmul(st.t[r], st.stp[r]);
  }
}

// ---------------- inverse iDFT core: 16 modes -> 48 outputs
struct InvState {
  float2 zr[16], t[16];
};

__device__ __forceinline__ void inv_init(InvState& st) {
#pragma unroll
  for (int m = 0; m < 16; ++m) st.t[m] = make_float2(1.f, 0.f);
}

__device__ __forceinline__ void inv_stepf(InvState& st, float2& o0, float2& o1, float2& o2) {
  constexpr int JG[16] = {0,1,2,0,1,2,0,1, 1,2,0,1,2,0,1,2};  // freq(m)%3
  float2 u0 = make_float2(0.f, 0.f), u1 = u0, u2 = u0;
#pragma unroll
  for (int m = 0; m < 16; ++m) {
    float2& uu = (JG[m] == 0) ? u0 : ((JG[m] == 1) ? u1 : u2);
    cfma(uu, st.zr[m], st.t[m]);
    const float2 stp = (m < 8) ? make_float2(FC0[m], FS0[m])
                               : make_float2(FC1[m - 8], FS1[m - 8]);
    st.t[m] = cmul(st.t[m], stp);
  }
  const float sx = u1.x + u2.x, sy = u1.y + u2.y;
  const float dx = u1.x - u2.x, dy = u1.y - u2.y;
  o0 = make_float2(u0.x + sx, u0.y + sy);
  const float tx = fmaf(-0.5f, sx, u0.x), ty = fmaf(-0.5f, sy, u0.y);
  const float ex = C866 * dx, ey = C866 * dy;
  o1 = make_float2(tx - ey, ty + ex);
  o2 = make_float2(tx + ey, ty - ex);
}

// ---------------- forward stage 1: DFT over W (direct global NT reads) -----
// in : x[b][d][h][w][ci][comp]; out: A[(bd*16+k3)*48+h][q] packed fp16
__global__ __launch_bounds__(192) void k_fwd_w(const float* __restrict__ x,
                                               uint32_t* __restrict__ A) {
  const int q = threadIdx.x % 96, half = threadIdx.x / 96;
  const int ci = q >> 2, c = q & 3;
  const float* xp = x + (size_t)blockIdx.x * 9216 + ci * 8;
  const int reo = c, imo = 7 - c;

  FwdState st;
  fwd_init(st, half);
#pragma unroll 4
  for (int j = 0; j < 16; ++j) {
    const float2 z0 = make_float2(__builtin_nontemporal_load(xp + j * 192 + reo),
                                  __builtin_nontemporal_load(xp + j * 192 + imo));
    const float2 z1 = make_float2(__builtin_nontemporal_load(xp + (j + 16) * 192 + reo),
                                  __builtin_nontemporal_load(xp + (j + 16) * 192 + imo));
    const float2 z2 = make_float2(__builtin_nontemporal_load(xp + (j + 32) * 192 + reo),
                                  __builtin_nontemporal_load(xp + (j + 32) * 192 + imo));
    fwd_stepf(st, z0, z1, z2);
  }
  const int bd = blockIdx.x / 48, h = blockIdx.x % 48;
  uint32_t* Ap = A + (((size_t)bd * 16 + half * 8) * 48 + h) * 96 + q;
#pragma unroll
  for (int r = 0; r < 8; ++r) Ap[(size_t)r * 4608] = c2h(st.acc[r]);
}

// ---------------- forward stage 2: DFT over H ----------------
// in : A[(bd*16+k3)*48+h][q] (h contig, NT); out: Bv[((b*256+k2*16+k3)*48)+d][q]
__global__ __launch_bounds__(192) void k_fwd_h(const uint32_t* __restrict__ A,
                                               uint32_t* __restrict__ Bv) {
  const int k3 = blockIdx.x & 15, bd = blockIdx.x >> 4;
  const int q = threadIdx.x % 96, half = threadIdx.x / 96;
  const uint32_t* Ap = A + ((size_t)bd * 16 + k3) * 4608 + q;  // + h*96
  FwdState st;
  fwd_init(st, half);
#pragma unroll 4
  for (int j = 0; j < 16; ++j) {
    const float2 z0 = h2c(__builtin_nontemporal_load(Ap + j * 96));
    const float2 z1 = h2c(__builtin_nontemporal_load(Ap + (j + 16) * 96));
    const float2 z2 = h2c(__builtin_nontemporal_load(Ap + (j + 32) * 96));
    fwd_stepf(st, z0, z1, z2);
  }
  const int b = bd / 48, d = bd % 48;
  uint32_t* Bp = Bv + (((size_t)b * 256 + half * 8 * 16 + k3) * 48 + d) * 96 + q;
#pragma unroll
  for (int r = 0; r < 8; ++r) Bp[(size_t)r * 73728] = c2h(st.acc[r]);
}

// ---------------- forward stage 3: DFT over D ----------------
// in : Bv[((b*256+k23)*48)+d][q] (d contig, NT); out: Cv[(b*4096+m1*256+k23)][q]
__global__ __launch_bounds__(192) void k_fwd_d(const uint32_t* __restrict__ Bv,
                                               uint32_t* __restrict__ Cv) {
  const int k23 = blockIdx.x & 255, b = blockIdx.x >> 8;
  const int q = threadIdx.x % 96, half = threadIdx.x / 96;
  const uint32_t* Bp = Bv + ((size_t)b * 256 + k23) * 4608 + q;  // + d*96
  FwdState st;
  fwd_init(st, half);
#pragma unroll 4
  for (int j = 0; j < 16; ++j) {
    const float2 z0 = h2c(__builtin_nontemporal_load(Bp + j * 96));
    const float2 z1 = h2c(__builtin_nontemporal_load(Bp + (j + 16) * 96));
    const float2 z2 = h2c(__builtin_nontemporal_load(Bp + (j + 32) * 96));
    fwd_stepf(st, z0, z1, z2);
  }
  uint32_t* Cp = Cv + ((size_t)b * 4096 + k23) * 96 + q;
#pragma unroll
  for (int r = 0; r < 8; ++r) Cp[(size_t)(half * 8 + r) * 24576] = c2h(st.acc[r]);
}

// ---------------- einsum: per-mode 192x192 Clifford matmul ----------------
// 256 threads: 64 modes x 4 co; blockIdx.z = ci-half -> partial buffer.
// wgt is single-use (NT); Cv is re-read ~24x (cached normal loads).
__global__ __launch_bounds__(256) void k_einsum(const uint32_t* __restrict__ Cv,
                                                const float* __restrict__ wgt,
                                                uint32_t* __restrict__ OMz) {
  const int mode = blockIdx.x * 64 + (threadIdx.x & 63);
  const int co = blockIdx.y * 4 + (threadIdx.x >> 6);
  const int cih = blockIdx.z;  // 0 or 1

  constexpr int WIDX[8][8] = {
      {0, 1, 2, 3, 4, 5, 6, 7}, {1, 0, 4, 5, 2, 3, 7, 6},
      {2, 4, 0, 6, 1, 7, 3, 5}, {3, 5, 6, 0, 7, 1, 2, 4},
      {4, 2, 1, 7, 0, 6, 5, 3}, {5, 3, 7, 1, 6, 0, 4, 2},
      {6, 7, 3, 2, 5, 4, 0, 1}, {7, 6, 5, 4, 3, 2, 1, 0}};
  constexpr int SGN[8][8] = {
      {1, 1, 1, 1, -1, -1, -1, -1}, {1, 1, -1, -1, 1, 1, -1, -1},
      {1, 1, 1, -1, -1, 1, 1, 1},   {1, 1, 1, 1, -1, -1, -1, -1},
      {1, 1, -1, 1, 1, -1, 1, 1},   {1, 1, -1, -1, 1, 1, -1, -1},
      {1, 1, 1, -1, -1, 1, 1, 1},   {1, 1, -1, 1, 1, -1, 1, 1}};

  float acc[8][4];
#pragma unroll
  for (int bo = 0; bo < 8; ++bo)
#pragma unroll
    for (int b = 0; b < 4; ++b) acc[bo][b] = 0.f;

#pragma unroll 2
  for (int cc = 0; cc < 12; ++cc) {
    const int ci = cih * 12 + cc;
    float w8[8];
#pragma unroll
    for (int k = 0; k < 8; ++k)
      w8[k] = __builtin_nontemporal_load(
          wgt + (size_t)((k * 24 + co) * 24 + ci) * 4096 + mode);
#pragma unroll
    for (int b = 0; b < 4; ++b) {
      const uint4 U = *(const uint4*)(Cv + ((size_t)(b * 4096 + mode) * 96 + ci * 4));
      const float2 z0 = h2c(U.x), z1 = h2c(U.y), z2 = h2c(U.z), z3 = h2c(U.w);
      const float inv[8] = {z0.x, z1.x, z2.x, z3.x, z3.y, z2.y, z1.y, z0.y};
#pragma unroll
      for (int bo = 0; bo < 8; ++bo) {
#pragma unroll
        for (int bi = 0; bi < 8; ++bi) {
          const float wv = w8[WIDX[bo][bi]];
          if (SGN[bo][bi] > 0)
            acc[bo][b] = fmaf(wv, inv[bi], acc[bo][b]);
          else
            acc[bo][b] = fmaf(wv, -inv[bi], acc[bo][b]);
        }
      }
    }
  }
  uint32_t* OMp = OMz + (size_t)cih * 1572864;
#pragma unroll
  for (int b = 0; b < 4; ++b) {
    uint4 P;
    P.x = c2h(make_float2(acc[0][b], acc[7][b]));
    P.y = c2h(make_float2(acc[1][b], acc[6][b]));
    P.z = c2h(make_float2(acc[2][b], acc[5][b]));
    P.w = c2h(make_float2(acc[3][b], acc[4][b]));
    *(uint4*)(OMp + ((size_t)(b * 4096 + mode) * 96 + co * 4)) = P;
  }
}

// ---------------- inverse stage 1: iDFT over D (16 -> 48) ----------------
// Sums the two einsum partials (NT reads). out: IS1[((b*48+d)*16+k3)*16+k2][q]
__global__ __launch_bounds__(192) void k_inv_d(const uint32_t* __restrict__ OMz,
                                               uint32_t* __restrict__ IS1) {
  const int col = blockIdx.x * 2 + threadIdx.x / 96;
  const int q = threadIdx.x % 96;
  const int k23 = col & 255, b = col >> 8;
  const int k2 = k23 >> 4, k3 = k23 & 15;
  InvState st;
#pragma unroll
  for (int m = 0; m < 16; ++m) {
    const size_t idx = ((size_t)b * 4096 + m * 256 + k23) * 96 + q;
    const float2 pa = h2c(__builtin_nontemporal_load(OMz + idx));
    const float2 pb = h2c(__builtin_nontemporal_load(OMz + idx + 1572864));
    st.zr[m] = make_float2(pa.x + pb.x, pa.y + pb.y);
  }
  inv_init(st);
  uint32_t* Op = IS1 + ((size_t)b * 12288 + k3 * 16 + k2) * 96 + q;  // + d*24576
#pragma unroll 2
  for (int j = 0; j < 16; ++j) {
    float2 o0, o1, o2;
    inv_stepf(st, o0, o1, o2);
    Op[(size_t)j * 24576] = c2h(o0);
    Op[(size_t)(j + 16) * 24576] = c2h(o1);
    Op[(size_t)(j + 32) * 24576] = c2h(o2);
  }
}

// ---------------- inverse stage 2: iDFT over H ----------------
// in : IS1[(bd*16+m3)*16+m2][q] (m2 contig, NT); out: IS2[(bd*48+h)*16+m3][q]
__global__ __launch_bounds__(192) void k_inv_h(const uint32_t* __restrict__ IS1,
                                               uint32_t* __restrict__ IS2) {
  const int col = blockIdx.x * 2 + threadIdx.x / 96;
  const int q = threadIdx.x % 96;
  const int m3 = col & 15, bd = col >> 4;
  const uint32_t* Ip = IS1 + ((size_t)bd * 256 + m3 * 16) * 96 + q;  // + m2*96
  InvState st;
#pragma unroll
  for (int m = 0; m < 16; ++m) st.zr[m] = h2c(__builtin_nontemporal_load(Ip + m * 96));
  inv_init(st);
  uint32_t* Op = IS2 + ((size_t)bd * 768 + m3) * 96 + q;  // + h*1536
#pragma unroll 2
  for (int j = 0; j < 16; ++j) {
    float2 o0, o1, o2;
    inv_stepf(st, o0, o1, o2);
    Op[(size_t)j * 1536] = c2h(o0);
    Op[(size_t)(j + 16) * 1536] = c2h(o1);
    Op[(size_t)(j + 32) * 1536] = c2h(o2);
  }
}

// ---------------- inverse stage 3: iDFT over W + writeout ----------------
// in : IS2[blk*16+m][q] (NT); out: fp32 scattered (normal stores).
__global__ __launch_bounds__(192) void k_inv_w(const uint32_t* __restrict__ IS2,
                                               float* __restrict__ out) {
  const int blk = blockIdx.x * 2 + threadIdx.x / 96;
  const int q = threadIdx.x % 96;
  const int co = q >> 2, c = q & 3;
  const float norm = 1.0f / 110592.0f;
  InvState st;
#pragma unroll
  for (int m = 0; m < 16; ++m) {
    float2 z = h2c(__builtin_nontemporal_load(IS2 + (size_t)blk * 16 * 96 + m * 96 + q));
    st.zr[m] = make_float2(z.x * norm, z.y * norm);
  }
  inv_init(st);
  float* ob = out + (size_t)blk * 9216 + co * 8;
#pragma unroll 2
  for (int j = 0; j < 16; ++j) {
    float2 o0, o1, o2;
    inv_stepf(st, o0, o1, o2);
    float* p0 = ob + (size_t)j * 192;
    float* p1 = ob + (size_t)(j + 16) * 192;
    float* p2 = ob + (size_t)(j + 32) * 192;
    p0[c] = o0.x; p0[7 - c] = o0.y;
    p1[c] = o1.x; p1[7 - c] = o1.y;
    p2[c] = o2.x; p2[7 - c] = o2.y;
  }
}

extern "C" void kernel_launch(void* const* d_in, const int* in_sizes, int n_in,
                              void* d_out, int out_size, void* d_ws, size_t ws_size,
                              hipStream_t stream) {
  (void)in_sizes; (void)n_in; (void)out_size; (void)ws_size;
  const float* x = (const float*)d_in[0];
  const float* wgt = (const float*)d_in[1];
  float* out = (float*)d_out;

  // Scratch inside d_out (339.7 MB), disjoint lifetimes, all fp16 packed:
  //   A   [0,        56623104)  fwd-W out   (live S1..S2)
  //   Bv  [56623104, 75497472)  fwd-H out   (live S2..S3)
  //   Cv  [75497472, 81788928)  fwd-D out   (live S3..E)
  //   OMz [81788928, 94371840)  einsum out, TWO ci-partials (live E..I1)
  //   IS1 [0,        18874368)  inv-D out   (A dead)
  // IS2 (56.6 MB) must not alias d_out -> d_ws.
  char* ob = (char*)d_out;
  uint32_t* A   = (uint32_t*)(ob + 0);
  uint32_t* Bv  = (uint32_t*)(ob + 56623104);
  uint32_t* Cv  = (uint32_t*)(ob + 75497472);
  uint32_t* OMz = (uint32_t*)(ob + 81788928);
  uint32_t* IS1 = (uint32_t*)(ob + 0);
  uint32_t* IS2 = (uint32_t*)d_ws;

  k_fwd_w<<<9216, 192, 0, stream>>>(x, A);
  k_fwd_h<<<3072, 192, 0, stream>>>(A, Bv);
  k_fwd_d<<<1024, 192, 0, stream>>>(Bv, Cv);
  k_einsum<<<dim3(64, 6, 2), 256, 0, stream>>>(Cv, wgt, OMz);
  k_inv_d<<<512, 192, 0, stream>>>(OMz, IS1);
  k_inv_h<<<1536, 192, 0, stream>>>(IS1, IS2);
  k_inv_w<<<4608, 192, 0, stream>>>(IS2, out);
}

// Round 14
// 297.246 us; speedup vs baseline: 1.0761x; 1.0761x over previous
//
#include <hip/hip_runtime.h>
#include <math.h>

// Clifford spectral conv: B=4, D=H=W=48, Cin=Cout=24, 16 modes/axis.
// q = ci*4 + c indexes 96 complex channels; d_c = x[...,c] + i*x[...,7-c].
// Radix-3 (48=3*16) DFT/iDFT, compile-time twiddle recurrence in registers.
// ALL intermediates packed fp16 complex (uint32). einsum ci-split x2.
// R14 = exact revert to R12 (best: 299.1 us). R13's NT loads regressed
// (+21us: defeated L1/L2 dedup of fwd_w twin loads + evicted producer's
// L3-resident intermediate lines). All cache-bypass variants are binned.
// Layouts (R8): A [bd][k3][h][q], Bv [b][k2k3][d][q], IS1 [b][d][k3][k2][q].

#define C866 0.8660254037844386f

constexpr float FC0[8] = {1.0f, 0.99144486137885f, 0.96592582628907f, 0.92387953251129f,
                          0.86602540378444f, 0.79335334029124f, 0.70710678118655f, 0.60876142900872f};
constexpr float FS0[8] = {0.0f, 0.13052619222005f, 0.25881904510252f, 0.38268343236509f,
                          0.5f, 0.60876142900872f, 0.70710678118655f, 0.79335334029124f};
constexpr float FC1[8] = {0.5f, 0.60876142900872f, 0.70710678118655f, 0.79335334029124f,
                          0.86602540378444f, 0.92387953251129f, 0.96592582628907f, 0.99144486137885f};
constexpr float FS1[8] = {-0.86602540378444f, -0.79335334029124f, -0.70710678118655f, -0.60876142900872f,
                          -0.5f, -0.38268343236509f, -0.25881904510252f, -0.13052619222005f};

__device__ __forceinline__ uint32_t c2h(float2 z) {
  union { _Float16 h[2]; uint32_t u; } v;
  v.h[0] = (_Float16)z.x; v.h[1] = (_Float16)z.y;
  return v.u;
}
__device__ __forceinline__ float2 h2c(uint32_t u) {
  union { uint32_t u; _Float16 h[2]; } v;
  v.u = u;
  return make_float2((float)v.h[0], (float)v.h[1]);
}

__device__ __forceinline__ float2 cmul(float2 a, float2 b) {
  return make_float2(fmaf(a.x, b.x, -(a.y * b.y)), fmaf(a.x, b.y, a.y * b.x));
}
__device__ __forceinline__ void cfma(float2& acc, float2 a, float2 t) {
  acc.x = fmaf(a.x, t.x, acc.x); acc.x = fmaf(-a.y, t.y, acc.x);
  acc.y = fmaf(a.x, t.y, acc.y); acc.y = fmaf(a.y, t.x, acc.y);
}

// ---------------- forward DFT core: 48 inputs -> 8 modes (this thread's half)
struct FwdState {
  float2 acc[8], t[8], stp[8];
  float2 R1, R2;
};

__device__ __forceinline__ void fwd_init(FwdState& st, int half) {
#pragma unroll
  for (int r = 0; r < 8; ++r) {
    st.acc[r] = make_float2(0.f, 0.f);
    st.t[r] = make_float2(1.f, 0.f);
    st.stp[r] = make_float2(half ? FC1[r] : FC0[r],
                            half ? -FS1[r] : -FS0[r]);  // e^{-i th k}
  }
  st.R1 = half ? make_float2(-0.5f, -C866) : make_float2(1.f, 0.f);
  st.R2 = half ? make_float2(-0.5f,  C866) : make_float2(1.f, 0.f);
}

__device__ __forceinline__ void fwd_stepf(FwdState& st, float2 z0, float2 z1, float2 z2) {
  z1 = cmul(z1, st.R1);
  z2 = cmul(z2, st.R2);
  const float sx = z1.x + z2.x, sy = z1.y + z2.y;
  const float dx = z1.x - z2.x, dy = z1.y - z2.y;
  const float2 y0 = make_float2(z0.x + sx, z0.y + sy);
  const float tx = fmaf(-0.5f, sx, z0.x), ty = fmaf(-0.5f, sy, z0.y);
  const float ex = C866 * dx, ey = C866 * dy;
  const float2 y1 = make_float2(tx + ey, ty - ex);
  const float2 y2 = make_float2(tx - ey, ty + ex);
#pragma unroll
  for (int r = 0; r < 8; ++r) {
    const float2 yy = (r % 3 == 0) ? y0 : ((r % 3 == 1) ? y1 : y2);
    cfma(st.acc[r], yy, st.t[r]);
    st.t[r] = cmul(st.t[r], st.stp[r]);
  }
}

// ---------------- inverse iDFT core: 16 modes -> 48 outputs
struct InvState {
  float2 zr[16], t[16];
};

__device__ __forceinline__ void inv_init(InvState& st) {
#pragma unroll
  for (int m = 0; m < 16; ++m) st.t[m] = make_float2(1.f, 0.f);
}

__device__ __forceinline__ void inv_stepf(InvState& st, float2& o0, float2& o1, float2& o2) {
  constexpr int JG[16] = {0,1,2,0,1,2,0,1, 1,2,0,1,2,0,1,2};  // freq(m)%3
  float2 u0 = make_float2(0.f, 0.f), u1 = u0, u2 = u0;
#pragma unroll
  for (int m = 0; m < 16; ++m) {
    float2& uu = (JG[m] == 0) ? u0 : ((JG[m] == 1) ? u1 : u2);
    cfma(uu, st.zr[m], st.t[m]);
    const float2 stp = (m < 8) ? make_float2(FC0[m], FS0[m])
                               : make_float2(FC1[m - 8], FS1[m - 8]);
    st.t[m] = cmul(st.t[m], stp);
  }
  const float sx = u1.x + u2.x, sy = u1.y + u2.y;
  const float dx = u1.x - u2.x, dy = u1.y - u2.y;
  o0 = make_float2(u0.x + sx, u0.y + sy);
  const float tx = fmaf(-0.5f, sx, u0.x), ty = fmaf(-0.5f, sy, u0.y);
  const float ex = C866 * dx, ey = C866 * dy;
  o1 = make_float2(tx - ey, ty + ex);
  o2 = make_float2(tx + ey, ty - ex);
}

// ---------------- forward stage 1: DFT over W (direct global reads) --------
// in : x[b][d][h][w][ci][comp]; out: A[(bd*16+k3)*48+h][q] packed fp16
__global__ __launch_bounds__(192) void k_fwd_w(const float* __restrict__ x,
                                               uint32_t* __restrict__ A) {
  const int q = threadIdx.x % 96, half = threadIdx.x / 96;
  const int ci = q >> 2, c = q & 3;
  const float* xp = x + (size_t)blockIdx.x * 9216 + ci * 8;
  const int reo = c, imo = 7 - c;

  FwdState st;
  fwd_init(st, half);
#pragma unroll 4
  for (int j = 0; j < 16; ++j) {
    const float2 z0 = make_float2(xp[j * 192 + reo], xp[j * 192 + imo]);
    const float2 z1 = make_float2(xp[(j + 16) * 192 + reo], xp[(j + 16) * 192 + imo]);
    const float2 z2 = make_float2(xp[(j + 32) * 192 + reo], xp[(j + 32) * 192 + imo]);
    fwd_stepf(st, z0, z1, z2);
  }
  const int bd = blockIdx.x / 48, h = blockIdx.x % 48;
  uint32_t* Ap = A + (((size_t)bd * 16 + half * 8) * 48 + h) * 96 + q;
#pragma unroll
  for (int r = 0; r < 8; ++r) Ap[(size_t)r * 4608] = c2h(st.acc[r]);
}

// ---------------- forward stage 2: DFT over H ----------------
// in : A[(bd*16+k3)*48+h][q] (h contig); out: Bv[((b*256+k2*16+k3)*48)+d][q]
__global__ __launch_bounds__(192) void k_fwd_h(const uint32_t* __restrict__ A,
                                               uint32_t* __restrict__ Bv) {
  const int k3 = blockIdx.x & 15, bd = blockIdx.x >> 4;
  const int q = threadIdx.x % 96, half = threadIdx.x / 96;
  const uint32_t* Ap = A + ((size_t)bd * 16 + k3) * 4608 + q;  // + h*96
  FwdState st;
  fwd_init(st, half);
#pragma unroll 4
  for (int j = 0; j < 16; ++j) {
    const float2 z0 = h2c(Ap[j * 96]);
    const float2 z1 = h2c(Ap[(j + 16) * 96]);
    const float2 z2 = h2c(Ap[(j + 32) * 96]);
    fwd_stepf(st, z0, z1, z2);
  }
  const int b = bd / 48, d = bd % 48;
  uint32_t* Bp = Bv + (((size_t)b * 256 + half * 8 * 16 + k3) * 48 + d) * 96 + q;
#pragma unroll
  for (int r = 0; r < 8; ++r) Bp[(size_t)r * 73728] = c2h(st.acc[r]);
}

// ---------------- forward stage 3: DFT over D ----------------
// in : Bv[((b*256+k23)*48)+d][q] (d contig); out: Cv[(b*4096+m1*256+k23)][q]
__global__ __launch_bounds__(192) void k_fwd_d(const uint32_t* __restrict__ Bv,
                                               uint32_t* __restrict__ Cv) {
  const int k23 = blockIdx.x & 255, b = blockIdx.x >> 8;
  const int q = threadIdx.x % 96, half = threadIdx.x / 96;
  const uint32_t* Bp = Bv + ((size_t)b * 256 + k23) * 4608 + q;  // + d*96
  FwdState st;
  fwd_init(st, half);
#pragma unroll 4
  for (int j = 0; j < 16; ++j) {
    const float2 z0 = h2c(Bp[j * 96]);
    const float2 z1 = h2c(Bp[(j + 16) * 96]);
    const float2 z2 = h2c(Bp[(j + 32) * 96]);
    fwd_stepf(st, z0, z1, z2);
  }
  uint32_t* Cp = Cv + ((size_t)b * 4096 + k23) * 96 + q;
#pragma unroll
  for (int r = 0; r < 8; ++r) Cp[(size_t)(half * 8 + r) * 24576] = c2h(st.acc[r]);
}

// ---------------- einsum: per-mode 192x192 Clifford matmul ----------------
// 256 threads: 64 modes x 4 co; blockIdx.z = ci-half -> partial buffer.
__global__ __launch_bounds__(256) void k_einsum(const uint32_t* __restrict__ Cv,
                                                const float* __restrict__ wgt,
                                                uint32_t* __restrict__ OMz) {
  const int mode = blockIdx.x * 64 + (threadIdx.x & 63);
  const int co = blockIdx.y * 4 + (threadIdx.x >> 6);
  const int cih = blockIdx.z;  // 0 or 1

  constexpr int WIDX[8][8] = {
      {0, 1, 2, 3, 4, 5, 6, 7}, {1, 0, 4, 5, 2, 3, 7, 6},
      {2, 4, 0, 6, 1, 7, 3, 5}, {3, 5, 6, 0, 7, 1, 2, 4},
      {4, 2, 1, 7, 0, 6, 5, 3}, {5, 3, 7, 1, 6, 0, 4, 2},
      {6, 7, 3, 2, 5, 4, 0, 1}, {7, 6, 5, 4, 3, 2, 1, 0}};
  constexpr int SGN[8][8] = {
      {1, 1, 1, 1, -1, -1, -1, -1}, {1, 1, -1, -1, 1, 1, -1, -1},
      {1, 1, 1, -1, -1, 1, 1, 1},   {1, 1, 1, 1, -1, -1, -1, -1},
      {1, 1, -1, 1, 1, -1, 1, 1},   {1, 1, -1, -1, 1, 1, -1, -1},
      {1, 1, 1, -1, -1, 1, 1, 1},   {1, 1, -1, 1, 1, -1, 1, 1}};

  float acc[8][4];
#pragma unroll
  for (int bo = 0; bo < 8; ++bo)
#pragma unroll
    for (int b = 0; b < 4; ++b) acc[bo][b] = 0.f;

#pragma unroll 2
  for (int cc = 0; cc < 12; ++cc) {
    const int ci = cih * 12 + cc;
    float w8[8];
#pragma unroll
    for (int k = 0; k < 8; ++k)
      w8[k] = wgt[(size_t)((k * 24 + co) * 24 + ci) * 4096 + mode];
#pragma unroll
    for (int b = 0; b < 4; ++b) {
      const uint4 U = *(const uint4*)(Cv + ((size_t)(b * 4096 + mode) * 96 + ci * 4));
      const float2 z0 = h2c(U.x), z1 = h2c(U.y), z2 = h2c(U.z), z3 = h2c(U.w);
      const float inv[8] = {z0.x, z1.x, z2.x, z3.x, z3.y, z2.y, z1.y, z0.y};
#pragma unroll
      for (int bo = 0; bo < 8; ++bo) {
#pragma unroll
        for (int bi = 0; bi < 8; ++bi) {
          const float wv = w8[WIDX[bo][bi]];
          if (SGN[bo][bi] > 0)
            acc[bo][b] = fmaf(wv, inv[bi], acc[bo][b]);
          else
            acc[bo][b] = fmaf(wv, -inv[bi], acc[bo][b]);
        }
      }
    }
  }
  uint32_t* OMp = OMz + (size_t)cih * 1572864;
#pragma unroll
  for (int b = 0; b < 4; ++b) {
    uint4 P;
    P.x = c2h(make_float2(acc[0][b], acc[7][b]));
    P.y = c2h(make_float2(acc[1][b], acc[6][b]));
    P.z = c2h(make_float2(acc[2][b], acc[5][b]));
    P.w = c2h(make_float2(acc[3][b], acc[4][b]));
    *(uint4*)(OMp + ((size_t)(b * 4096 + mode) * 96 + co * 4)) = P;
  }
}

// ---------------- inverse stage 1: iDFT over D (16 -> 48) ----------------
// Sums the two einsum partials. out: IS1[((b*48+d)*16+k3)*16+k2][q]
__global__ __launch_bounds__(192) void k_inv_d(const uint32_t* __restrict__ OMz,
                                               uint32_t* __restrict__ IS1) {
  const int col = blockIdx.x * 2 + threadIdx.x / 96;
  const int q = threadIdx.x % 96;
  const int k23 = col & 255, b = col >> 8;
  const int k2 = k23 >> 4, k3 = k23 & 15;
  InvState st;
#pragma unroll
  for (int m = 0; m < 16; ++m) {
    const size_t idx = ((size_t)b * 4096 + m * 256 + k23) * 96 + q;
    const float2 pa = h2c(OMz[idx]);
    const float2 pb = h2c(OMz[idx + 1572864]);
    st.zr[m] = make_float2(pa.x + pb.x, pa.y + pb.y);
  }
  inv_init(st);
  uint32_t* Op = IS1 + ((size_t)b * 12288 + k3 * 16 + k2) * 96 + q;  // + d*24576
#pragma unroll 2
  for (int j = 0; j < 16; ++j) {
    float2 o0, o1, o2;
    inv_stepf(st, o0, o1, o2);
    Op[(size_t)j * 24576] = c2h(o0);
    Op[(size_t)(j + 16) * 24576] = c2h(o1);
    Op[(size_t)(j + 32) * 24576] = c2h(o2);
  }
}

// ---------------- inverse stage 2: iDFT over H ----------------
// in : IS1[(bd*16+m3)*16+m2][q] (m2 contig); out: IS2[(bd*48+h)*16+m3][q]
__global__ __launch_bounds__(192) void k_inv_h(const uint32_t* __restrict__ IS1,
                                               uint32_t* __restrict__ IS2) {
  const int col = blockIdx.x * 2 + threadIdx.x / 96;
  const int q = threadIdx.x % 96;
  const int m3 = col & 15, bd = col >> 4;
  const uint32_t* Ip = IS1 + ((size_t)bd * 256 + m3 * 16) * 96 + q;  // + m2*96
  InvState st;
#pragma unroll
  for (int m = 0; m < 16; ++m) st.zr[m] = h2c(Ip[m * 96]);
  inv_init(st);
  uint32_t* Op = IS2 + ((size_t)bd * 768 + m3) * 96 + q;  // + h*1536
#pragma unroll 2
  for (int j = 0; j < 16; ++j) {
    float2 o0, o1, o2;
    inv_stepf(st, o0, o1, o2);
    Op[(size_t)j * 1536] = c2h(o0);
    Op[(size_t)(j + 16) * 1536] = c2h(o1);
    Op[(size_t)(j + 32) * 1536] = c2h(o2);
  }
}

// ---------------- inverse stage 3: iDFT over W + writeout ----------------
__global__ __launch_bounds__(192) void k_inv_w(const uint32_t* __restrict__ IS2,
                                               float* __restrict__ out) {
  const int blk = blockIdx.x * 2 + threadIdx.x / 96;
  const int q = threadIdx.x % 96;
  const int co = q >> 2, c = q & 3;
  const float norm = 1.0f / 110592.0f;
  InvState st;
#pragma unroll
  for (int m = 0; m < 16; ++m) {
    float2 z = h2c(IS2[((size_t)blk * 16 + m) * 96 + q]);
    st.zr[m] = make_float2(z.x * norm, z.y * norm);
  }
  inv_init(st);
  float* ob = out + (size_t)blk * 9216 + co * 8;
#pragma unroll 2
  for (int j = 0; j < 16; ++j) {
    float2 o0, o1, o2;
    inv_stepf(st, o0, o1, o2);
    float* p0 = ob + (size_t)j * 192;
    float* p1 = ob + (size_t)(j + 16) * 192;
    float* p2 = ob + (size_t)(j + 32) * 192;
    p0[c] = o0.x; p0[7 - c] = o0.y;
    p1[c] = o1.x; p1[7 - c] = o1.y;
    p2[c] = o2.x; p2[7 - c] = o2.y;
  }
}

extern "C" void kernel_launch(void* const* d_in, const int* in_sizes, int n_in,
                              void* d_out, int out_size, void* d_ws, size_t ws_size,
                              hipStream_t stream) {
  (void)in_sizes; (void)n_in; (void)out_size; (void)ws_size;
  const float* x = (const float*)d_in[0];
  const float* wgt = (const float*)d_in[1];
  float* out = (float*)d_out;

  // Scratch inside d_out (339.7 MB), disjoint lifetimes, all fp16 packed:
  //   A   [0,        56623104)  fwd-W out   (live S1..S2)
  //   Bv  [56623104, 75497472)  fwd-H out   (live S2..S3)
  //   Cv  [75497472, 81788928)  fwd-D out   (live S3..E)
  //   OMz [81788928, 94371840)  einsum out, TWO ci-partials (live E..I1)
  //   IS1 [0,        18874368)  inv-D out   (A dead)
  // IS2 (56.6 MB) must not alias d_out -> d_ws.
  char* ob = (char*)d_out;
  uint32_t* A   = (uint32_t*)(ob + 0);
  uint32_t* Bv  = (uint32_t*)(ob + 56623104);
  uint32_t* Cv  = (uint32_t*)(ob + 75497472);
  uint32_t* OMz = (uint32_t*)(ob + 81788928);
  uint32_t* IS1 = (uint32_t*)(ob + 0);
  uint32_t* IS2 = (uint32_t*)d_ws;

  k_fwd_w<<<9216, 192, 0, stream>>>(x, A);
  k_fwd_h<<<3072, 192, 0, stream>>>(A, Bv);
  k_fwd_d<<<1024, 192, 0, stream>>>(Bv, Cv);
  k_einsum<<<dim3(64, 6, 2), 256, 0, stream>>>(Cv, wgt, OMz);
  k_inv_d<<<512, 192, 0, stream>>>(OMz, IS1);
  k_inv_h<<<1536, 192, 0, stream>>>(IS1, IS2);
  k_inv_w<<<4608, 192, 0, stream>>>(IS2, out);
}